// Round 5
// baseline (1032.347 us; speedup 1.0000x reference)
//
#include <hip/hip_runtime.h>

typedef __attribute__((ext_vector_type(8))) short bf16x8;
typedef __attribute__((ext_vector_type(4))) float f32x4;

__device__ __forceinline__ float b2f(unsigned short u) {
    union { unsigned int i; float f; } v; v.i = ((unsigned int)u) << 16; return v.f;
}
__device__ __forceinline__ unsigned short f2b(float f) {
    union { float f; unsigned int i; } u; u.f = f;
    return (unsigned short)((u.i + 0x7FFFu + ((u.i >> 16) & 1u)) >> 16);
}
__device__ __forceinline__ unsigned int packbf2(float a, float b) {
    return (unsigned int)f2b(a) | ((unsigned int)f2b(b) << 16);
}

#define LDAB 40   // bf16 LDS row stride for 32-k staging tiles
#define KLD 136   // bf16 LDS row stride for full-K (128) tiles

// ---------------------------------------------------------------------------
// ego f32 -> bf16
// ---------------------------------------------------------------------------
__global__ __launch_bounds__(256) void cvt_kernel(
    const float* __restrict__ in, unsigned short* __restrict__ out, int n8)
{
    int i = blockIdx.x * 256 + threadIdx.x;
    if (i >= n8) return;
    const float* p = in + (size_t)i * 8;
    float4 a = *(const float4*)p, b = *(const float4*)(p + 4);
    uint4 pk;
    pk.x = packbf2(a.x, a.y); pk.y = packbf2(a.z, a.w);
    pk.z = packbf2(b.x, b.y); pk.w = packbf2(b.z, b.w);
    *(uint4*)(out + (size_t)i * 8) = pk;
}

// ---------------------------------------------------------------------------
// rows sorted -> CSR row_ptr via per-row lower_bound. row_ptr has N+1 entries.
// ---------------------------------------------------------------------------
__global__ __launch_bounds__(256) void rowptr_kernel(
    const int* __restrict__ rows, int* __restrict__ row_ptr, int nnz, int N)
{
    int r = blockIdx.x * 256 + threadIdx.x;
    if (r > N) return;
    int lo = 0, hi = nnz;
    while (lo < hi) {
        int mid = (lo + hi) >> 1;
        if (rows[mid] < r) lo = mid + 1; else hi = mid;
    }
    row_ptr[r] = lo;
}

// ---------------------------------------------------------------------------
// Fused SpMM + bi-interaction. Block = 256 thr = 4 waves, 64 rows.
// Phase 1: wave computes side for its 16 rows via CSR walk (depth-8 register
//          pipeline; each edge = one coalesced 256B wave load of bf16 ego),
//          writes (ego+side)/(ego*side) as bf16 MFMA tiles in LDS.
// Phase 2: 64x128 MFMA GEMM vs W1/W2, leaky+leaky epilogue -> agg.
// side never exists in global memory; zero atomics.
// ---------------------------------------------------------------------------
__global__ __launch_bounds__(256) void bi_fused(
    const unsigned short* __restrict__ egoH, const float* __restrict__ vals,
    const int* __restrict__ cols, const int* __restrict__ row_ptr,
    const float* __restrict__ W1, const float* __restrict__ b1,
    const float* __restrict__ W2, const float* __restrict__ b2,
    float* __restrict__ out, int M)
{
    __shared__ unsigned short Us[64 * KLD];
    __shared__ unsigned short Ms[64 * KLD];
    __shared__ unsigned short W1s[128 * LDAB];
    __shared__ unsigned short W2s[128 * LDAB];

    int tid = threadIdx.x, wave = tid >> 6, lane = tid & 63;
    int lm = lane & 15, quad = lane >> 4;
    int bm = blockIdx.x * 64;
    int c2 = lane * 2;

    // ---- phase 1: side + U/M tiles ----
    for (int sub = 0; sub < 16; ++sub) {
        int lr = wave * 16 + sub;
        int row = bm + lr;
        float ax = 0.f, ay = 0.f;
        float ex = 0.f, ey = 0.f;
        if (row < M) {
            int e0 = row_ptr[row], e1 = row_ptr[row + 1];
            int e = e0;
            int c0 = e1 - e; if (c0 > 8) c0 = 8;
            float pv[8]; unsigned int pg[8];
            #pragma unroll
            for (int j = 0; j < 8; ++j) {
                if (j < c0) {
                    pv[j] = vals[e + j];
                    pg[j] = *(const unsigned int*)(egoH + (size_t)cols[e + j] * 128 + c2);
                }
            }
            while (c0 > 0) {
                int e2 = e + 8;
                int cn = e1 - e2; if (cn > 8) cn = 8; if (cn < 0) cn = 0;
                float qv[8]; unsigned int qg[8];
                #pragma unroll
                for (int j = 0; j < 8; ++j) {
                    if (j < cn) {
                        qv[j] = vals[e2 + j];
                        qg[j] = *(const unsigned int*)(egoH + (size_t)cols[e2 + j] * 128 + c2);
                    }
                }
                #pragma unroll
                for (int j = 0; j < 8; ++j) {
                    if (j < c0) {
                        ax = fmaf(pv[j], b2f((unsigned short)(pg[j] & 0xffffu)), ax);
                        ay = fmaf(pv[j], b2f((unsigned short)(pg[j] >> 16)), ay);
                    }
                }
                #pragma unroll
                for (int j = 0; j < 8; ++j) { pv[j] = qv[j]; pg[j] = qg[j]; }
                e = e2; c0 = cn;
            }
            unsigned int eg = *(const unsigned int*)(egoH + (size_t)row * 128 + c2);
            ex = b2f((unsigned short)(eg & 0xffffu));
            ey = b2f((unsigned short)(eg >> 16));
        }
        *(unsigned int*)&Us[lr * KLD + c2] = packbf2(ex + ax, ey + ay);
        *(unsigned int*)&Ms[lr * KLD + c2] = packbf2(ex * ax, ey * ay);
    }
    __syncthreads();

    // ---- phase 2: MFMA ----
    f32x4 acc1[8], acc2[8];
    #pragma unroll
    for (int j = 0; j < 8; ++j) { acc1[j] = (f32x4)(0.f); acc2[j] = (f32x4)(0.f); }

    for (int k0 = 0; k0 < 128; k0 += 32) {
        #pragma unroll
        for (int it = 0; it < 2; ++it) {
            int nn = tid & 127;
            int kq = (tid >> 7) * 8 + it * 16;
            const float* p1 = W1 + (size_t)(k0 + kq) * 128 + nn;
            const float* p2 = W2 + (size_t)(k0 + kq) * 128 + nn;
            float wa[8], wb[8];
            #pragma unroll
            for (int j = 0; j < 8; ++j) { wa[j] = p1[(size_t)j * 128]; wb[j] = p2[(size_t)j * 128]; }
            uint4 pk1, pk2;
            pk1.x = packbf2(wa[0],wa[1]); pk1.y = packbf2(wa[2],wa[3]);
            pk1.z = packbf2(wa[4],wa[5]); pk1.w = packbf2(wa[6],wa[7]);
            pk2.x = packbf2(wb[0],wb[1]); pk2.y = packbf2(wb[2],wb[3]);
            pk2.z = packbf2(wb[4],wb[5]); pk2.w = packbf2(wb[6],wb[7]);
            *(uint4*)&W1s[nn * LDAB + kq] = pk1;
            *(uint4*)&W2s[nn * LDAB + kq] = pk2;
        }
        __syncthreads();
        bf16x8 au = *(bf16x8*)&Us[(wave * 16 + lm) * KLD + k0 + quad * 8];
        bf16x8 am = *(bf16x8*)&Ms[(wave * 16 + lm) * KLD + k0 + quad * 8];
        #pragma unroll
        for (int ni = 0; ni < 8; ++ni) {
            bf16x8 f1 = *(bf16x8*)&W1s[(ni * 16 + lm) * LDAB + quad * 8];
            acc1[ni] = __builtin_amdgcn_mfma_f32_16x16x32_bf16(au, f1, acc1[ni], 0, 0, 0);
            bf16x8 f2 = *(bf16x8*)&W2s[(ni * 16 + lm) * LDAB + quad * 8];
            acc2[ni] = __builtin_amdgcn_mfma_f32_16x16x32_bf16(am, f2, acc2[ni], 0, 0, 0);
        }
        __syncthreads();
    }
    #pragma unroll
    for (int r = 0; r < 4; ++r) {
        int row = bm + wave * 16 + quad * 4 + r;
        if (row < M) {
            #pragma unroll
            for (int ni = 0; ni < 8; ++ni) {
                int col = ni * 16 + lm;
                float v1 = acc1[ni][r] + b1[col];
                v1 = v1 > 0.f ? v1 : 0.01f * v1;
                float v2 = acc2[ni][r] + b2[col];
                v2 = v2 > 0.f ? v2 : 0.01f * v2;
                out[(size_t)row * 128 + col] = v1 + v2;
            }
        }
    }
}

// ---------------------------------------------------------------------------
// 128x(N-tile 128) MFMA GEMM core. 4 waves x 32 rows, 2 m-frags x 8 n-frags.
// Optional residual + fused LayerNorm (requires N==128, bn==0), optional relu.
// ---------------------------------------------------------------------------
__device__ __forceinline__ void gemm128_core(
    const float* __restrict__ A, const float* __restrict__ W,
    const float* __restrict__ bias, const float* __restrict__ R,
    const float* __restrict__ lng, const float* __restrict__ lnb,
    float* __restrict__ C, int M, int N, int K, int act, int doLN,
    int bm, int bn, unsigned short* As, unsigned short* Bs)
{
    int tid = threadIdx.x, wave = tid >> 6, lane = tid & 63;
    int lm = lane & 15, quad = lane >> 4;

    f32x4 acc[2][8];
    #pragma unroll
    for (int i = 0; i < 2; ++i)
        #pragma unroll
        for (int j = 0; j < 8; ++j) acc[i][j] = (f32x4)(0.f);

    for (int k0 = 0; k0 < K; k0 += 32) {
        // A: 128 rows x 32 k
        #pragma unroll
        for (int it = 0; it < 2; ++it) {
            int i = tid + it * 256;
            int m = i >> 2, kc = (i & 3) * 8;
            const float* p = A + (size_t)(bm + m) * K + k0 + kc;
            float4 x0 = *(const float4*)p, x1 = *(const float4*)(p + 4);
            uint4 pk;
            pk.x = packbf2(x0.x, x0.y); pk.y = packbf2(x0.z, x0.w);
            pk.z = packbf2(x1.x, x1.y); pk.w = packbf2(x1.z, x1.w);
            *(uint4*)&As[m * LDAB + kc] = pk;
        }
        // B transposed to [n][k]: 128 n x 32 k
        #pragma unroll
        for (int it = 0; it < 2; ++it) {
            int nn = tid & 127;
            int kq = (tid >> 7) * 8 + it * 16;
            const float* p = W + (size_t)(k0 + kq) * N + bn + nn;
            float w[8];
            #pragma unroll
            for (int j = 0; j < 8; ++j) w[j] = p[(size_t)j * N];
            uint4 pk;
            pk.x = packbf2(w[0], w[1]); pk.y = packbf2(w[2], w[3]);
            pk.z = packbf2(w[4], w[5]); pk.w = packbf2(w[6], w[7]);
            *(uint4*)&Bs[nn * LDAB + kq] = pk;
        }
        __syncthreads();
        bf16x8 af[2];
        #pragma unroll
        for (int mi = 0; mi < 2; ++mi)
            af[mi] = *(bf16x8*)&As[(wave * 32 + mi * 16 + lm) * LDAB + quad * 8];
        #pragma unroll
        for (int ni = 0; ni < 8; ++ni) {
            bf16x8 bf = *(bf16x8*)&Bs[(ni * 16 + lm) * LDAB + quad * 8];
            #pragma unroll
            for (int mi = 0; mi < 2; ++mi)
                acc[mi][ni] = __builtin_amdgcn_mfma_f32_16x16x32_bf16(
                    af[mi], bf, acc[mi][ni], 0, 0, 0);
        }
        __syncthreads();
    }

    #pragma unroll
    for (int mi = 0; mi < 2; ++mi) {
        #pragma unroll
        for (int r = 0; r < 4; ++r) {
            int row = bm + wave * 32 + mi * 16 + quad * 4 + r;
            float v[8];
            #pragma unroll
            for (int ni = 0; ni < 8; ++ni) {
                int col = bn + ni * 16 + lm;
                v[ni] = acc[mi][ni][r] + bias[col];
                if (R) v[ni] += R[(size_t)row * N + col];
                if (act) v[ni] = fmaxf(v[ni], 0.f);
            }
            if (doLN) {
                float s = 0.f, ss = 0.f;
                #pragma unroll
                for (int ni = 0; ni < 8; ++ni) { s += v[ni]; ss += v[ni] * v[ni]; }
                #pragma unroll
                for (int o = 1; o < 16; o <<= 1) {
                    s  += __shfl_xor(s, o, 64);
                    ss += __shfl_xor(ss, o, 64);
                }
                float mean = s * (1.f / 128.f);
                float var = ss * (1.f / 128.f) - mean * mean;
                float rstd = rsqrtf(var + 1e-5f);
                #pragma unroll
                for (int ni = 0; ni < 8; ++ni) {
                    int col = ni * 16 + lm;
                    C[(size_t)row * 128 + col] =
                        (v[ni] - mean) * rstd * lng[col] + lnb[col];
                }
            } else {
                #pragma unroll
                for (int ni = 0; ni < 8; ++ni)
                    C[(size_t)row * N + bn + ni * 16 + lm] = v[ni];
            }
        }
    }
}

__global__ __launch_bounds__(256) void gemm128(
    const float* __restrict__ A, const float* __restrict__ W,
    const float* __restrict__ bias, float* __restrict__ C,
    int M, int N, int K, int act)
{
    __shared__ unsigned short As[128 * LDAB];
    __shared__ unsigned short Bs[128 * LDAB];
    gemm128_core(A, W, bias, nullptr, nullptr, nullptr, C, M, N, K, act, 0,
                 blockIdx.y * 128, blockIdx.x * 128, As, Bs);
}

__global__ __launch_bounds__(256) void gemm128_ln(
    const float* __restrict__ A, const float* __restrict__ W,
    const float* __restrict__ bias, const float* __restrict__ R,
    const float* __restrict__ lng, const float* __restrict__ lnb,
    float* __restrict__ C, int M, int K)
{
    __shared__ unsigned short As[128 * LDAB];
    __shared__ unsigned short Bs[128 * LDAB];
    gemm128_core(A, W, bias, R, lng, lnb, C, M, 128, K, 0, 1,
                 blockIdx.x * 128, 0, As, Bs);
}

__global__ __launch_bounds__(256) void qkv128(
    const float* __restrict__ A,
    const float* __restrict__ wq, const float* __restrict__ wk, const float* __restrict__ wv,
    const float* __restrict__ bq, const float* __restrict__ bk, const float* __restrict__ bv,
    float* __restrict__ Q, float* __restrict__ Ko, float* __restrict__ V, int M)
{
    __shared__ unsigned short As[128 * LDAB];
    __shared__ unsigned short Bs[128 * LDAB];
    int sel = blockIdx.x;
    const float* W = (sel == 0) ? wq : (sel == 1) ? wk : wv;
    const float* b = (sel == 0) ? bq : (sel == 1) ? bk : bv;
    float* C = (sel == 0) ? Q : (sel == 1) ? Ko : V;
    gemm128_core(A, W, b, nullptr, nullptr, nullptr, C, M, 128, 128, 0, 0,
                 blockIdx.y * 128, 0, As, Bs);
}

// ---------------------------------------------------------------------------
// Attention: block = (b, h, half of queries), 128 threads, single-pass
// online softmax. L == 256, DK == 16.
// ---------------------------------------------------------------------------
__global__ __launch_bounds__(128) void attn_kernel(
    const float* __restrict__ q, const float* __restrict__ k,
    const float* __restrict__ v, float* __restrict__ o, int NH)
{
    const int L = 256, DK = 16;
    __shared__ float Ks[L * DK];
    __shared__ float Vs[L * DK];
    int bh = blockIdx.x >> 1;
    int half = blockIdx.x & 1;
    int b = bh / NH, h = bh % NH;
    int tid = threadIdx.x;

    for (int i = tid; i < L * 4; i += 128) {
        int l = i >> 2, d4 = (i & 3) * 4;
        size_t g = ((size_t)(b * L + l) * NH + h) * DK + d4;
        *(float4*)&Ks[l * 16 + d4] = *(const float4*)(k + g);
        *(float4*)&Vs[l * 16 + d4] = *(const float4*)(v + g);
    }
    __syncthreads();

    int l = half * 128 + tid;
    size_t qbase = ((size_t)(b * L + l) * NH + h) * DK;
    float qr[16];
    #pragma unroll
    for (int d4 = 0; d4 < 4; ++d4) {
        float4 t = *(const float4*)(q + qbase + d4 * 4);
        qr[d4*4+0] = t.x * 0.25f; qr[d4*4+1] = t.y * 0.25f;
        qr[d4*4+2] = t.z * 0.25f; qr[d4*4+3] = t.w * 0.25f;
    }
    float acc[16];
    #pragma unroll
    for (int d = 0; d < 16; ++d) acc[d] = 0.f;
    float mmax = -1e30f, ssum = 0.f;
    for (int kk = 0; kk < L; ++kk) {
        float dot = 0.f;
        #pragma unroll
        for (int d4 = 0; d4 < 4; ++d4) {
            float4 kv = *(const float4*)&Ks[kk * 16 + d4 * 4];
            dot = fmaf(qr[d4*4+0], kv.x, dot);
            dot = fmaf(qr[d4*4+1], kv.y, dot);
            dot = fmaf(qr[d4*4+2], kv.z, dot);
            dot = fmaf(qr[d4*4+3], kv.w, dot);
        }
        if (dot > mmax) {
            float alpha = __expf(mmax - dot);
            ssum *= alpha;
            #pragma unroll
            for (int d = 0; d < 16; ++d) acc[d] *= alpha;
            mmax = dot;
        }
        float p = __expf(dot - mmax);
        ssum += p;
        #pragma unroll
        for (int d4 = 0; d4 < 4; ++d4) {
            float4 vv = *(const float4*)&Vs[kk * 16 + d4 * 4];
            acc[d4*4+0] = fmaf(p, vv.x, acc[d4*4+0]);
            acc[d4*4+1] = fmaf(p, vv.y, acc[d4*4+1]);
            acc[d4*4+2] = fmaf(p, vv.z, acc[d4*4+2]);
            acc[d4*4+3] = fmaf(p, vv.w, acc[d4*4+3]);
        }
    }
    float inv = 1.f / ssum;
    #pragma unroll
    for (int d4 = 0; d4 < 4; ++d4) {
        float4 t;
        t.x = acc[d4*4+0] * inv; t.y = acc[d4*4+1] * inv;
        t.z = acc[d4*4+2] * inv; t.w = acc[d4*4+3] * inv;
        *(float4*)(o + qbase + d4 * 4) = t;
    }
}

extern "C" void kernel_launch(void* const* d_in, const int* in_sizes, int n_in,
                              void* d_out, int out_size, void* d_ws, size_t ws_size,
                              hipStream_t stream) {
    const float* ego    = (const float*)d_in[0];
    const float* vals   = (const float*)d_in[1];
    const float* W1     = (const float*)d_in[2];
    const float* b1     = (const float*)d_in[3];
    const float* W2     = (const float*)d_in[4];
    const float* b2     = (const float*)d_in[5];
    const float* enc_in = (const float*)d_in[6];
    const float* wq  = (const float*)d_in[7];
    const float* bq  = (const float*)d_in[8];
    const float* wk  = (const float*)d_in[9];
    const float* bk  = (const float*)d_in[10];
    const float* wv  = (const float*)d_in[11];
    const float* bv  = (const float*)d_in[12];
    const float* wo  = (const float*)d_in[13];
    const float* bo  = (const float*)d_in[14];
    const float* ln1_g = (const float*)d_in[15];
    const float* ln1_b = (const float*)d_in[16];
    const float* cw1 = (const float*)d_in[17];
    const float* cb1 = (const float*)d_in[18];
    const float* cw2 = (const float*)d_in[19];
    const float* cb2 = (const float*)d_in[20];
    const float* ln2_g = (const float*)d_in[21];
    const float* ln2_b = (const float*)d_in[22];
    const int* rows = (const int*)d_in[23];
    const int* cols = (const int*)d_in[24];

    const int D = 128, DI = 512, NH = 8, L = 256;
    const int Nn   = in_sizes[0] / D;        // 100000
    const int nnz  = in_sizes[1];            // 2000000
    const int NL   = in_sizes[7] / (D * D);  // 2
    const int Menc = in_sizes[6] / D;        // 8192
    const int Bb   = Menc / L;               // 32

    float* ws = (float*)d_ws;
    size_t off = 0;
    unsigned short* egoH = (unsigned short*)(ws + off); off += (size_t)Nn * D / 2;
    int* row_ptr = (int*)(ws + off); off += (size_t)Nn + 8;
    float* Qb = ws + off; off += (size_t)Menc * D;
    float* Kb = ws + off; off += (size_t)Menc * D;
    float* Vb = ws + off; off += (size_t)Menc * D;
    float* Ob = ws + off; off += (size_t)Menc * D;
    float* XA = ws + off; off += (size_t)Menc * D;
    float* XB = ws + off; off += (size_t)Menc * D;
    float* Hb = ws + off; off += (size_t)Menc * DI;

    float* outAgg = (float*)d_out;
    float* outX   = (float*)d_out + (size_t)Nn * D;

    // ---- Part A: cvt + rowptr + fused SpMM/bi-interaction ----
    cvt_kernel<<<(Nn * D / 8 + 255) / 256, 256, 0, stream>>>(ego, egoH, Nn * D / 8);
    rowptr_kernel<<<(Nn + 256) / 256, 256, 0, stream>>>(rows, row_ptr, nnz, Nn);
    bi_fused<<<(Nn + 63) / 64, 256, 0, stream>>>(
        egoH, vals, cols, row_ptr, W1, b1, W2, b2, outAgg, Nn);

    // ---- Part B: transformer encoder ----
    const float* x = enc_in;
    for (int i = 0; i < NL; ++i) {
        const size_t wOff = (size_t)i * D * D;
        qkv128<<<dim3(3, Menc / 128), 256, 0, stream>>>(
            x, wq + wOff, wk + wOff, wv + wOff,
            bq + (size_t)i * D, bk + (size_t)i * D, bv + (size_t)i * D,
            Qb, Kb, Vb, Menc);
        attn_kernel<<<Bb * NH * 2, 128, 0, stream>>>(Qb, Kb, Vb, Ob, NH);
        gemm128_ln<<<Menc / 128, 256, 0, stream>>>(
            Ob, wo + wOff, bo + (size_t)i * D, x,
            ln1_g + (size_t)i * D, ln1_b + (size_t)i * D, XA, Menc, D);
        gemm128<<<dim3(DI / 128, Menc / 128), 256, 0, stream>>>(
            XA, cw1 + (size_t)i * D * DI, cb1 + (size_t)i * DI, Hb, Menc, DI, D, 1);
        float* dst = (i == NL - 1) ? outX : XB;
        gemm128_ln<<<Menc / 128, 256, 0, stream>>>(
            Hb, cw2 + (size_t)i * DI * D, cb2 + (size_t)i * D, XA,
            ln2_g + (size_t)i * D, ln2_b + (size_t)i * D, dst, Menc, DI);
        x = XB;
    }
}

// Round 6
// 654.766 us; speedup vs baseline: 1.5767x; 1.5767x over previous
//
#include <hip/hip_runtime.h>

typedef __attribute__((ext_vector_type(8))) short bf16x8;
typedef __attribute__((ext_vector_type(4))) float f32x4;

__device__ __forceinline__ float b2f(unsigned short u) {
    union { unsigned int i; float f; } v; v.i = ((unsigned int)u) << 16; return v.f;
}
__device__ __forceinline__ unsigned short f2b(float f) {
    union { float f; unsigned int i; } u; u.f = f;
    return (unsigned short)((u.i + 0x7FFFu + ((u.i >> 16) & 1u)) >> 16);
}
__device__ __forceinline__ unsigned int packbf2(float a, float b) {
    return (unsigned int)f2b(a) | ((unsigned int)f2b(b) << 16);
}

#define LDAB 40   // bf16 LDS row stride for 32-k staging tiles

// ---------------------------------------------------------------------------
// f32 -> bf16 bulk convert (8 elems/thread)
// ---------------------------------------------------------------------------
__global__ __launch_bounds__(256) void cvt_kernel(
    const float* __restrict__ in, unsigned short* __restrict__ out, int n8)
{
    int i = blockIdx.x * 256 + threadIdx.x;
    if (i >= n8) return;
    const float* p = in + (size_t)i * 8;
    float4 a = *(const float4*)p, b = *(const float4*)(p + 4);
    uint4 pk;
    pk.x = packbf2(a.x, a.y); pk.y = packbf2(a.z, a.w);
    pk.z = packbf2(b.x, b.y); pk.w = packbf2(b.z, b.w);
    *(uint4*)(out + (size_t)i * 8) = pk;
}

// ---------------------------------------------------------------------------
// SpMM: side[r,:] += vals[e] * egoH[cols[e],:]  (rows sorted, ego bf16).
// Block 256 = 4 waves; wave owns 128 edges; lane owns 2 cols (uint gather =
// 256B/wave/edge). Depth-8 register prefetch queue; atomic flush only at
// row boundaries (long 128-edge segments -> few flushes).
// ---------------------------------------------------------------------------
__global__ __launch_bounds__(256) void spmm_kernel(
    const unsigned short* __restrict__ egoH, const float* __restrict__ vals,
    const int* __restrict__ rows, const int* __restrict__ cols,
    float* __restrict__ side, int nnz)
{
    __shared__ int s_row[512];
    __shared__ int s_col[512];
    __shared__ float s_val[512];
    int e0 = blockIdx.x * 512;
    int n = nnz - e0; if (n > 512) n = 512;
    int tid = threadIdx.x;
    for (int i = tid; i < n; i += 256) {
        s_row[i] = rows[e0 + i];
        s_col[i] = cols[e0 + i];
        s_val[i] = vals[e0 + i];
    }
    __syncthreads();

    int wave = tid >> 6, lane = tid & 63;
    int base = wave * 128;
    int cnt = n - base; if (cnt > 128) cnt = 128;
    if (cnt <= 0) return;
    int c2 = lane * 2;

    unsigned int pg[8]; float dummy = 0.f;
    #pragma unroll
    for (int j = 0; j < 8; ++j) {
        if (j < cnt) pg[j] = *(const unsigned int*)(egoH + (size_t)s_col[base + j] * 128 + c2);
        else pg[j] = 0;
    }
    float ax = 0.f, ay = 0.f;
    int cur = s_row[base];
    for (int eo = 0; eo < 128; eo += 8) {
        if (eo >= cnt) break;
        #pragma unroll
        for (int j = 0; j < 8; ++j) {
            int e = eo + j;
            if (e < cnt) {
                int r = s_row[base + e];
                float vv = s_val[base + e];
                unsigned int g = pg[j];
                int nx = e + 8;
                if (nx < cnt)
                    pg[j] = *(const unsigned int*)(egoH + (size_t)s_col[base + nx] * 128 + c2);
                if (r != cur) {
                    atomicAdd(&side[(size_t)cur * 128 + c2 + 0], ax);
                    atomicAdd(&side[(size_t)cur * 128 + c2 + 1], ay);
                    ax = 0.f; ay = 0.f; cur = r;
                }
                ax = fmaf(vv, b2f((unsigned short)(g & 0xffffu)), ax);
                ay = fmaf(vv, b2f((unsigned short)(g >> 16)), ay);
            }
        }
    }
    atomicAdd(&side[(size_t)cur * 128 + c2 + 0], ax);
    atomicAdd(&side[(size_t)cur * 128 + c2 + 1], ay);
    (void)dummy;
}

// ---------------------------------------------------------------------------
// Bi-interaction fused MFMA GEMM (64x128 tile, ego bf16 + side f32):
//   agg = leaky((ego+side)@W1+b1) + leaky((ego*side)@W2+b2)  -> f32 out
// ---------------------------------------------------------------------------
__global__ __launch_bounds__(256) void bi_gemm64(
    const unsigned short* __restrict__ egoH, const float* __restrict__ side,
    const float* __restrict__ W1, const float* __restrict__ b1,
    const float* __restrict__ W2, const float* __restrict__ b2,
    float* __restrict__ out, int M)
{
    __shared__ unsigned short Us[64 * LDAB];
    __shared__ unsigned short Ms[64 * LDAB];
    __shared__ unsigned short W1s[128 * LDAB];
    __shared__ unsigned short W2s[128 * LDAB];

    int tid = threadIdx.x, wave = tid >> 6, lane = tid & 63;
    int lm = lane & 15, quad = lane >> 4;
    int bm = blockIdx.x * 64;

    f32x4 acc1[8], acc2[8];
    #pragma unroll
    for (int j = 0; j < 8; ++j) { acc1[j] = (f32x4)(0.f); acc2[j] = (f32x4)(0.f); }

    for (int k0 = 0; k0 < 128; k0 += 32) {
        {
            int m = tid >> 2, kc = (tid & 3) * 8;
            int gm = bm + m;
            float e[8], s[8];
            if (gm < M) {
                union { uint4 v; unsigned short h[8]; } eu;
                eu.v = *(const uint4*)(egoH + (size_t)gm * 128 + k0 + kc);
                const float* ps = side + (size_t)gm * 128 + k0 + kc;
                float4 s0 = *(const float4*)ps, s1 = *(const float4*)(ps + 4);
                #pragma unroll
                for (int j = 0; j < 8; ++j) e[j] = b2f(eu.h[j]);
                s[0]=s0.x; s[1]=s0.y; s[2]=s0.z; s[3]=s0.w;
                s[4]=s1.x; s[5]=s1.y; s[6]=s1.z; s[7]=s1.w;
            } else {
                #pragma unroll
                for (int j = 0; j < 8; ++j) { e[j] = 0.f; s[j] = 0.f; }
            }
            uint4 pu, pm;
            pu.x = packbf2(e[0]+s[0], e[1]+s[1]); pu.y = packbf2(e[2]+s[2], e[3]+s[3]);
            pu.z = packbf2(e[4]+s[4], e[5]+s[5]); pu.w = packbf2(e[6]+s[6], e[7]+s[7]);
            pm.x = packbf2(e[0]*s[0], e[1]*s[1]); pm.y = packbf2(e[2]*s[2], e[3]*s[3]);
            pm.z = packbf2(e[4]*s[4], e[5]*s[5]); pm.w = packbf2(e[6]*s[6], e[7]*s[7]);
            *(uint4*)&Us[m * LDAB + kc] = pu;
            *(uint4*)&Ms[m * LDAB + kc] = pm;
        }
        #pragma unroll
        for (int it = 0; it < 2; ++it) {
            int nn = tid & 127;
            int kq = (tid >> 7) * 8 + it * 16;
            const float* p1 = W1 + (size_t)(k0 + kq) * 128 + nn;
            const float* p2 = W2 + (size_t)(k0 + kq) * 128 + nn;
            float wa[8], wb[8];
            #pragma unroll
            for (int j = 0; j < 8; ++j) { wa[j] = p1[(size_t)j * 128]; wb[j] = p2[(size_t)j * 128]; }
            uint4 pk1, pk2;
            pk1.x = packbf2(wa[0],wa[1]); pk1.y = packbf2(wa[2],wa[3]);
            pk1.z = packbf2(wa[4],wa[5]); pk1.w = packbf2(wa[6],wa[7]);
            pk2.x = packbf2(wb[0],wb[1]); pk2.y = packbf2(wb[2],wb[3]);
            pk2.z = packbf2(wb[4],wb[5]); pk2.w = packbf2(wb[6],wb[7]);
            *(uint4*)&W1s[nn * LDAB + kq] = pk1;
            *(uint4*)&W2s[nn * LDAB + kq] = pk2;
        }
        __syncthreads();
        bf16x8 au = *(bf16x8*)&Us[(wave * 16 + lm) * LDAB + quad * 8];
        bf16x8 am = *(bf16x8*)&Ms[(wave * 16 + lm) * LDAB + quad * 8];
        #pragma unroll
        for (int ni = 0; ni < 8; ++ni) {
            bf16x8 f1 = *(bf16x8*)&W1s[(ni * 16 + lm) * LDAB + quad * 8];
            acc1[ni] = __builtin_amdgcn_mfma_f32_16x16x32_bf16(au, f1, acc1[ni], 0, 0, 0);
            bf16x8 f2 = *(bf16x8*)&W2s[(ni * 16 + lm) * LDAB + quad * 8];
            acc2[ni] = __builtin_amdgcn_mfma_f32_16x16x32_bf16(am, f2, acc2[ni], 0, 0, 0);
        }
        __syncthreads();
    }
    #pragma unroll
    for (int r = 0; r < 4; ++r) {
        int row = bm + wave * 16 + quad * 4 + r;
        if (row < M) {
            #pragma unroll
            for (int ni = 0; ni < 8; ++ni) {
                int col = ni * 16 + lm;
                float v1 = acc1[ni][r] + b1[col];
                v1 = v1 > 0.f ? v1 : 0.01f * v1;
                float v2 = acc2[ni][r] + b2[col];
                v2 = v2 > 0.f ? v2 : 0.01f * v2;
                out[(size_t)row * 128 + col] = v1 + v2;
            }
        }
    }
}

// ---------------------------------------------------------------------------
// 128x128 MFMA GEMM core; A is bf16 (M,K) (no pack on staging), W f32 (K,N).
// Residual (bf16) + fused LayerNorm optional; output bf16 (Cb) or f32 (Cf).
// ---------------------------------------------------------------------------
__device__ __forceinline__ void gemm128_core(
    const unsigned short* __restrict__ A, const float* __restrict__ W,
    const float* __restrict__ bias, const unsigned short* __restrict__ R,
    const float* __restrict__ lng, const float* __restrict__ lnb,
    unsigned short* __restrict__ Cb, float* __restrict__ Cf,
    int M, int N, int K, int act, int doLN,
    int bm, int bn, unsigned short* As, unsigned short* Bs)
{
    int tid = threadIdx.x, wave = tid >> 6, lane = tid & 63;
    int lm = lane & 15, quad = lane >> 4;

    f32x4 acc[2][8];
    #pragma unroll
    for (int i = 0; i < 2; ++i)
        #pragma unroll
        for (int j = 0; j < 8; ++j) acc[i][j] = (f32x4)(0.f);

    for (int k0 = 0; k0 < K; k0 += 32) {
        // A: 128 rows x 32 k, bf16 -> straight 16B copies
        #pragma unroll
        for (int it = 0; it < 2; ++it) {
            int i = tid + it * 256;
            int m = i >> 2, kc = (i & 3) * 8;
            uint4 v = *(const uint4*)(A + (size_t)(bm + m) * K + k0 + kc);
            *(uint4*)&As[m * LDAB + kc] = v;
        }
        // B transposed to [n][k]: 128 n x 32 k (f32 -> bf16 pack)
        #pragma unroll
        for (int it = 0; it < 2; ++it) {
            int nn = tid & 127;
            int kq = (tid >> 7) * 8 + it * 16;
            const float* p = W + (size_t)(k0 + kq) * N + bn + nn;
            float w[8];
            #pragma unroll
            for (int j = 0; j < 8; ++j) w[j] = p[(size_t)j * N];
            uint4 pk;
            pk.x = packbf2(w[0], w[1]); pk.y = packbf2(w[2], w[3]);
            pk.z = packbf2(w[4], w[5]); pk.w = packbf2(w[6], w[7]);
            *(uint4*)&Bs[nn * LDAB + kq] = pk;
        }
        __syncthreads();
        bf16x8 af[2];
        #pragma unroll
        for (int mi = 0; mi < 2; ++mi)
            af[mi] = *(bf16x8*)&As[(wave * 32 + mi * 16 + lm) * LDAB + quad * 8];
        #pragma unroll
        for (int ni = 0; ni < 8; ++ni) {
            bf16x8 bf = *(bf16x8*)&Bs[(ni * 16 + lm) * LDAB + quad * 8];
            #pragma unroll
            for (int mi = 0; mi < 2; ++mi)
                acc[mi][ni] = __builtin_amdgcn_mfma_f32_16x16x32_bf16(
                    af[mi], bf, acc[mi][ni], 0, 0, 0);
        }
        __syncthreads();
    }

    #pragma unroll
    for (int mi = 0; mi < 2; ++mi) {
        #pragma unroll
        for (int r = 0; r < 4; ++r) {
            int row = bm + wave * 32 + mi * 16 + quad * 4 + r;
            float v[8];
            #pragma unroll
            for (int ni = 0; ni < 8; ++ni) {
                int col = bn + ni * 16 + lm;
                v[ni] = acc[mi][ni][r] + bias[col];
                if (R) v[ni] += b2f(R[(size_t)row * N + col]);
                if (act) v[ni] = fmaxf(v[ni], 0.f);
            }
            if (doLN) {
                float s = 0.f, ss = 0.f;
                #pragma unroll
                for (int ni = 0; ni < 8; ++ni) { s += v[ni]; ss += v[ni] * v[ni]; }
                #pragma unroll
                for (int o = 1; o < 16; o <<= 1) {
                    s  += __shfl_xor(s, o, 64);
                    ss += __shfl_xor(ss, o, 64);
                }
                float mean = s * (1.f / 128.f);
                float var = ss * (1.f / 128.f) - mean * mean;
                float rstd = rsqrtf(var + 1e-5f);
                #pragma unroll
                for (int ni = 0; ni < 8; ++ni)
                    v[ni] = (v[ni] - mean) * rstd * lng[ni * 16 + lm] + lnb[ni * 16 + lm];
            }
            if (Cf) {
                #pragma unroll
                for (int ni = 0; ni < 8; ++ni)
                    Cf[(size_t)row * N + bn + ni * 16 + lm] = v[ni];
            } else {
                #pragma unroll
                for (int ni = 0; ni < 8; ++ni)
                    Cb[(size_t)row * N + bn + ni * 16 + lm] = f2b(v[ni]);
            }
        }
    }
}

__global__ __launch_bounds__(256) void gemm128(
    const unsigned short* __restrict__ A, const float* __restrict__ W,
    const float* __restrict__ bias, unsigned short* __restrict__ C,
    int M, int N, int K, int act)
{
    __shared__ unsigned short As[128 * LDAB];
    __shared__ unsigned short Bs[128 * LDAB];
    gemm128_core(A, W, bias, nullptr, nullptr, nullptr, C, nullptr,
                 M, N, K, act, 0, blockIdx.y * 128, blockIdx.x * 128, As, Bs);
}

__global__ __launch_bounds__(256) void gemm128_ln(
    const unsigned short* __restrict__ A, const float* __restrict__ W,
    const float* __restrict__ bias, const unsigned short* __restrict__ R,
    const float* __restrict__ lng, const float* __restrict__ lnb,
    unsigned short* __restrict__ Cb, float* __restrict__ Cf, int M, int K)
{
    __shared__ unsigned short As[128 * LDAB];
    __shared__ unsigned short Bs[128 * LDAB];
    gemm128_core(A, W, bias, R, lng, lnb, Cb, Cf,
                 M, 128, K, 0, 1, blockIdx.x * 128, 0, As, Bs);
}

__global__ __launch_bounds__(256) void qkv128(
    const unsigned short* __restrict__ A,
    const float* __restrict__ wq, const float* __restrict__ wk, const float* __restrict__ wv,
    const float* __restrict__ bq, const float* __restrict__ bk, const float* __restrict__ bv,
    unsigned short* __restrict__ Q, unsigned short* __restrict__ Ko,
    unsigned short* __restrict__ V, int M)
{
    __shared__ unsigned short As[128 * LDAB];
    __shared__ unsigned short Bs[128 * LDAB];
    int sel = blockIdx.x;
    const float* W = (sel == 0) ? wq : (sel == 1) ? wk : wv;
    const float* b = (sel == 0) ? bq : (sel == 1) ? bk : bv;
    unsigned short* C = (sel == 0) ? Q : (sel == 1) ? Ko : V;
    gemm128_core(A, W, b, nullptr, nullptr, nullptr, C, nullptr,
                 M, 128, 128, 0, 0, blockIdx.y * 128, 0, As, Bs);
}

// ---------------------------------------------------------------------------
// Attention on bf16 Q/K/V -> bf16 O. Block = (b,h,half), 128 threads,
// single-pass online softmax. L=256, DK=16.
// ---------------------------------------------------------------------------
__global__ __launch_bounds__(128) void attn_kernel(
    const unsigned short* __restrict__ q, const unsigned short* __restrict__ k,
    const unsigned short* __restrict__ v, unsigned short* __restrict__ o, int NH)
{
    const int L = 256;
    __shared__ float Ks[L * 16];
    __shared__ float Vs[L * 16];
    int bh = blockIdx.x >> 1;
    int half = blockIdx.x & 1;
    int b = bh / NH, h = bh % NH;
    int tid = threadIdx.x;

    for (int i = tid; i < L * 2; i += 128) {
        int l = i >> 1, d8 = (i & 1) * 8;
        size_t g = ((size_t)(b * L + l) * NH + h) * 16 + d8;
        union { uint4 u; unsigned short s[8]; } kv, vv;
        kv.u = *(const uint4*)(k + g);
        vv.u = *(const uint4*)(v + g);
        #pragma unroll
        for (int j = 0; j < 8; ++j) {
            Ks[l * 16 + d8 + j] = b2f(kv.s[j]);
            Vs[l * 16 + d8 + j] = b2f(vv.s[j]);
        }
    }
    __syncthreads();

    int l = half * 128 + tid;
    size_t qbase = ((size_t)(b * L + l) * NH + h) * 16;
    float qr[16];
    {
        union { uint4 u; unsigned short s[8]; } q0, q1;
        q0.u = *(const uint4*)(q + qbase);
        q1.u = *(const uint4*)(q + qbase + 8);
        #pragma unroll
        for (int j = 0; j < 8; ++j) {
            qr[j] = b2f(q0.s[j]) * 0.25f;
            qr[8 + j] = b2f(q1.s[j]) * 0.25f;
        }
    }
    float acc[16];
    #pragma unroll
    for (int d = 0; d < 16; ++d) acc[d] = 0.f;
    float mmax = -1e30f, ssum = 0.f;
    for (int kk = 0; kk < L; ++kk) {
        float dot = 0.f;
        #pragma unroll
        for (int d4 = 0; d4 < 4; ++d4) {
            float4 kv = *(const float4*)&Ks[kk * 16 + d4 * 4];
            dot = fmaf(qr[d4*4+0], kv.x, dot);
            dot = fmaf(qr[d4*4+1], kv.y, dot);
            dot = fmaf(qr[d4*4+2], kv.z, dot);
            dot = fmaf(qr[d4*4+3], kv.w, dot);
        }
        if (dot > mmax) {
            float alpha = __expf(mmax - dot);
            ssum *= alpha;
            #pragma unroll
            for (int d = 0; d < 16; ++d) acc[d] *= alpha;
            mmax = dot;
        }
        float p = __expf(dot - mmax);
        ssum += p;
        #pragma unroll
        for (int d4 = 0; d4 < 4; ++d4) {
            float4 vv = *(const float4*)&Vs[kk * 16 + d4 * 4];
            acc[d4*4+0] = fmaf(p, vv.x, acc[d4*4+0]);
            acc[d4*4+1] = fmaf(p, vv.y, acc[d4*4+1]);
            acc[d4*4+2] = fmaf(p, vv.z, acc[d4*4+2]);
            acc[d4*4+3] = fmaf(p, vv.w, acc[d4*4+3]);
        }
    }
    float inv = 1.f / ssum;
    uint4 o0, o1;
    o0.x = packbf2(acc[0]*inv, acc[1]*inv);  o0.y = packbf2(acc[2]*inv, acc[3]*inv);
    o0.z = packbf2(acc[4]*inv, acc[5]*inv);  o0.w = packbf2(acc[6]*inv, acc[7]*inv);
    o1.x = packbf2(acc[8]*inv, acc[9]*inv);  o1.y = packbf2(acc[10]*inv, acc[11]*inv);
    o1.z = packbf2(acc[12]*inv, acc[13]*inv); o1.w = packbf2(acc[14]*inv, acc[15]*inv);
    *(uint4*)(o + qbase) = o0;
    *(uint4*)(o + qbase + 8) = o1;
}

extern "C" void kernel_launch(void* const* d_in, const int* in_sizes, int n_in,
                              void* d_out, int out_size, void* d_ws, size_t ws_size,
                              hipStream_t stream) {
    const float* ego    = (const float*)d_in[0];
    const float* vals   = (const float*)d_in[1];
    const float* W1     = (const float*)d_in[2];
    const float* b1     = (const float*)d_in[3];
    const float* W2     = (const float*)d_in[4];
    const float* b2     = (const float*)d_in[5];
    const float* enc_in = (const float*)d_in[6];
    const float* wq  = (const float*)d_in[7];
    const float* bq  = (const float*)d_in[8];
    const float* wk  = (const float*)d_in[9];
    const float* bk  = (const float*)d_in[10];
    const float* wv  = (const float*)d_in[11];
    const float* bv  = (const float*)d_in[12];
    const float* wo  = (const float*)d_in[13];
    const float* bo  = (const float*)d_in[14];
    const float* ln1_g = (const float*)d_in[15];
    const float* ln1_b = (const float*)d_in[16];
    const float* cw1 = (const float*)d_in[17];
    const float* cb1 = (const float*)d_in[18];
    const float* cw2 = (const float*)d_in[19];
    const float* cb2 = (const float*)d_in[20];
    const float* ln2_g = (const float*)d_in[21];
    const float* ln2_b = (const float*)d_in[22];
    const int* rows = (const int*)d_in[23];
    const int* cols = (const int*)d_in[24];

    const int D = 128, DI = 512, NH = 8, L = 256;
    const int Nn   = in_sizes[0] / D;        // 100000
    const int nnz  = in_sizes[1];            // 2000000
    const int NL   = in_sizes[7] / (D * D);  // 2
    const int Menc = in_sizes[6] / D;        // 8192
    const int Bb   = Menc / L;               // 32

    float* ws = (float*)d_ws;
    size_t off = 0;
    unsigned short* egoH = (unsigned short*)(ws + off); off += (size_t)Nn * D / 2;
    float* side = ws + off; off += (size_t)Nn * D;
    // bf16 activation buffers (each Menc*D bf16 = Menc*D/2 floats)
    unsigned short* Xin = (unsigned short*)(ws + off); off += (size_t)Menc * D / 2;
    unsigned short* Qb  = (unsigned short*)(ws + off); off += (size_t)Menc * D / 2;
    unsigned short* Kb  = (unsigned short*)(ws + off); off += (size_t)Menc * D / 2;
    unsigned short* Vb  = (unsigned short*)(ws + off); off += (size_t)Menc * D / 2;
    unsigned short* Ob  = (unsigned short*)(ws + off); off += (size_t)Menc * D / 2;
    unsigned short* XA  = (unsigned short*)(ws + off); off += (size_t)Menc * D / 2;
    unsigned short* XB  = (unsigned short*)(ws + off); off += (size_t)Menc * D / 2;
    unsigned short* Hb  = (unsigned short*)(ws + off); off += (size_t)Menc * DI / 2;

    float* outAgg = (float*)d_out;
    float* outX   = (float*)d_out + (size_t)Nn * D;

    // ---- Part A: cvt + SpMM + bi-interaction ----
    cvt_kernel<<<(Nn * D / 8 + 255) / 256, 256, 0, stream>>>(ego, egoH, Nn * D / 8);
    hipMemsetAsync(side, 0, (size_t)Nn * D * sizeof(float), stream);
    spmm_kernel<<<(nnz + 511) / 512, 256, 0, stream>>>(egoH, vals, rows, cols, side, nnz);
    bi_gemm64<<<(Nn + 63) / 64, 256, 0, stream>>>(
        egoH, side, W1, b1, W2, b2, outAgg, Nn);

    // ---- Part B: transformer encoder (bf16 activations) ----
    cvt_kernel<<<(Menc * D / 8 + 255) / 256, 256, 0, stream>>>(enc_in, Xin, Menc * D / 8);
    const unsigned short* x = Xin;
    for (int i = 0; i < NL; ++i) {
        const size_t wOff = (size_t)i * D * D;
        qkv128<<<dim3(3, Menc / 128), 256, 0, stream>>>(
            x, wq + wOff, wk + wOff, wv + wOff,
            bq + (size_t)i * D, bk + (size_t)i * D, bv + (size_t)i * D,
            Qb, Kb, Vb, Menc);
        attn_kernel<<<Bb * NH * 2, 128, 0, stream>>>(Qb, Kb, Vb, Ob, NH);
        gemm128_ln<<<Menc / 128, 256, 0, stream>>>(
            Ob, wo + wOff, bo + (size_t)i * D, x,
            ln1_g + (size_t)i * D, ln1_b + (size_t)i * D, XA, nullptr, Menc, D);
        gemm128<<<dim3(DI / 128, Menc / 128), 256, 0, stream>>>(
            XA, cw1 + (size_t)i * D * DI, cb1 + (size_t)i * DI, Hb, Menc, DI, D, 1);
        if (i == NL - 1) {
            gemm128_ln<<<Menc / 128, 256, 0, stream>>>(
                Hb, cw2 + (size_t)i * DI * D, cb2 + (size_t)i * D, XA,
                ln2_g + (size_t)i * D, ln2_b + (size_t)i * D, nullptr, outX, Menc, DI);
        } else {
            gemm128_ln<<<Menc / 128, 256, 0, stream>>>(
                Hb, cw2 + (size_t)i * DI * D, cb2 + (size_t)i * D, XA,
                ln2_g + (size_t)i * D, ln2_b + (size_t)i * D, XB, nullptr, Menc, DI);
            x = XB;
        }
    }
}